// Round 14
// baseline (424.391 us; speedup 1.0000x reference)
//
#include <hip/hip_runtime.h>

#define HDIM 64
#define CAP_M 96
#define CAP_U 32
#define OVF_MAX 65536

typedef __attribute__((ext_vector_type(8))) short bf16x8;   // 8 bf16 (4 VGPRs)
typedef __attribute__((ext_vector_type(4))) float f32x4;    // 4 fp32

// ---------------- bf16 helpers ----------------
__device__ __forceinline__ float bf2f(unsigned short u) {
  unsigned int x = ((unsigned int)u) << 16;
  return __uint_as_float(x);
}
__device__ __forceinline__ unsigned short f2bf(float f) {
  unsigned int x = __float_as_uint(f);
  unsigned int r = (x + 0x7FFFu + ((x >> 16) & 1u)) >> 16;  // RNE
  return (unsigned short)r;
}

// ---------------- init: zero meta + bf16 table copies (one dispatch) ----------------
__global__ __launch_bounds__(256) void k_init(int* __restrict__ meta, int nmeta,
                                              const float* __restrict__ ut,
                                              unsigned short* __restrict__ ub, int n8u,
                                              const float* __restrict__ mt,
                                              unsigned short* __restrict__ mb, int n8m) {
  int bid = blockIdx.x;
  if (bid < 512) {
    int i = bid * 256 + threadIdx.x;
    for (int j = i; j < nmeta; j += 512 * 256) meta[j] = 0;
  } else if (bid < 512 + 2048) {
    int i = (bid - 512) * 256 + threadIdx.x;
    for (int j = i; j < n8u; j += 2048 * 256) {
      const float4* p = (const float4*)(ut + (size_t)j * 8);
      float4 a = p[0], b = p[1];
      uint4 o;
      o.x = (unsigned int)f2bf(a.x) | ((unsigned int)f2bf(a.y) << 16);
      o.y = (unsigned int)f2bf(a.z) | ((unsigned int)f2bf(a.w) << 16);
      o.z = (unsigned int)f2bf(b.x) | ((unsigned int)f2bf(b.y) << 16);
      o.w = (unsigned int)f2bf(b.z) | ((unsigned int)f2bf(b.w) << 16);
      *(uint4*)(ub + (size_t)j * 8) = o;
    }
  } else {
    int i = (bid - 512 - 2048) * 256 + threadIdx.x;
    for (int j = i; j < n8m; j += 512 * 256) {
      const float4* p = (const float4*)(mt + (size_t)j * 8);
      float4 a = p[0], b = p[1];
      uint4 o;
      o.x = (unsigned int)f2bf(a.x) | ((unsigned int)f2bf(a.y) << 16);
      o.y = (unsigned int)f2bf(a.z) | ((unsigned int)f2bf(a.w) << 16);
      o.z = (unsigned int)f2bf(b.x) | ((unsigned int)f2bf(b.y) << 16);
      o.w = (unsigned int)f2bf(b.z) | ((unsigned int)f2bf(b.w) << 16);
      *(uint4*)(mb + (size_t)j * 8) = o;
    }
  }
}

// ---------------- fused bucket fill (r7/r12 proven; atomic-floor ~172us) ----------------
__global__ __launch_bounds__(256) void k_fillb2_x(const int* __restrict__ srcU,
                                                  const int* __restrict__ dstM,
                                                  int* __restrict__ curM,
                                                  int* __restrict__ bktM,
                                                  int* __restrict__ ovfM_cnt,
                                                  int* __restrict__ ovfM,
                                                  int* __restrict__ curU,
                                                  unsigned short* __restrict__ bktU,
                                                  int* __restrict__ ovfU_cnt,
                                                  int* __restrict__ ovfU,
                                                  int E, int NM_, int NU_) {
  int xg = blockIdx.x & 7;
  int mlo = (int)(((long long)NM_ * xg) >> 3);
  int mhi = (xg == 7) ? NM_ : (int)(((long long)NM_ * (xg + 1)) >> 3);
  int ulo = (int)(((long long)NU_ * xg) >> 3);
  int uhi = (xg == 7) ? NU_ : (int)(((long long)NU_ * (xg + 1)) >> 3);
  int li = (blockIdx.x >> 3) * blockDim.x + threadIdx.x;
  int stride = (gridDim.x >> 3) * blockDim.x;
  int E4 = E >> 2;
  const int4* s4 = (const int4*)srcU;
  const int4* d4 = (const int4*)dstM;
  for (int e = li; e < E4; e += stride) {
    int4 d = d4[e];
    int4 s = s4[e];
#pragma unroll
    for (int k = 0; k < 4; ++k) {
      int dd = (k == 0) ? d.x : (k == 1) ? d.y : (k == 2) ? d.z : d.w;
      int ss = (k == 0) ? s.x : (k == 1) ? s.y : (k == 2) ? s.z : s.w;
      if (dd >= mlo && dd < mhi) {
        int p = atomicAdd(&curM[dd], 1);
        if (p < CAP_M) bktM[(size_t)dd * CAP_M + p] = ss;
        else { int q = atomicAdd(ovfM_cnt, 1); if (q < OVF_MAX) { ovfM[2 * q] = dd; ovfM[2 * q + 1] = ss; } }
      }
      if (ss >= ulo && ss < uhi) {
        int p = atomicAdd(&curU[ss], 1);
        if (p < CAP_U) bktU[(size_t)ss * CAP_U + p] = (unsigned short)dd;
        else { int q = atomicAdd(ovfU_cnt, 1); if (q < OVF_MAX) { ovfU[2 * q] = ss; ovfU[2 * q + 1] = dd; } }
      }
    }
  }
  for (int e = E4 * 4 + li; e < E; e += stride) {
    int dd = dstM[e];
    int ss = srcU[e];
    if (dd >= mlo && dd < mhi) {
      int p = atomicAdd(&curM[dd], 1);
      if (p < CAP_M) bktM[(size_t)dd * CAP_M + p] = ss;
      else { int q = atomicAdd(ovfM_cnt, 1); if (q < OVF_MAX) { ovfM[2 * q] = dd; ovfM[2 * q + 1] = ss; } }
    }
    if (ss >= ulo && ss < uhi) {
      int p = atomicAdd(&curU[ss], 1);
      if (p < CAP_U) bktU[(size_t)ss * CAP_U + p] = (unsigned short)dd;
      else { int q = atomicAdd(ovfU_cnt, 1); if (q < OVF_MAX) { ovfU[2 * q] = ss; ovfU[2 * q + 1] = dd; } }
    }
  }
}

// ---------------- aggregation: 8 lanes/node, 16B loads, 8-deep in-flight window ----------------
__device__ __forceinline__ void acc8(float4& a, float4& b, uint4 w) {
  a.x += __uint_as_float(w.x << 16);
  a.y += __uint_as_float(w.x & 0xFFFF0000u);
  a.z += __uint_as_float(w.y << 16);
  a.w += __uint_as_float(w.y & 0xFFFF0000u);
  b.x += __uint_as_float(w.z << 16);
  b.y += __uint_as_float(w.z & 0xFFFF0000u);
  b.z += __uint_as_float(w.w << 16);
  b.w += __uint_as_float(w.w & 0xFFFF0000u);
}

template <typename IT>
__global__ __launch_bounds__(256) void k_agg8(const unsigned short* __restrict__ xb,
                                              const int* __restrict__ cur,
                                              const IT* __restrict__ bkt,
                                              int cap,
                                              float* __restrict__ agg,
                                              int n_dst) {
  int t = threadIdx.x;
  int q = t & 7;                        // col octet: cols 8q..8q+7
  int gg = (blockIdx.x * 256 + t) >> 3; // node
  int stride = (gridDim.x * 256) >> 3;

  for (int node = gg; node < n_dst; node += stride) {
    int deg = cur[node];
    int nb = deg < cap ? deg : cap;
    const IT* lst = bkt + (size_t)node * cap;
    float4 a = make_float4(0.f, 0.f, 0.f, 0.f);
    float4 b = a;
    int e = 0;
    // 8-deep main loop: 8 independent row loads in flight per iteration
    for (; e + 8 <= nb; e += 8) {
      int i0, i1, i2, i3, i4, i5, i6, i7;
      if (sizeof(IT) == 2) {
        uint4 ia = *(const uint4*)&lst[e];   // 8 ushorts in one 16B load
        i0 = ia.x & 0xFFFF; i1 = ia.x >> 16;
        i2 = ia.y & 0xFFFF; i3 = ia.y >> 16;
        i4 = ia.z & 0xFFFF; i5 = ia.z >> 16;
        i6 = ia.w & 0xFFFF; i7 = ia.w >> 16;
      } else {
        int4 a0 = *(const int4*)&lst[e];
        int4 a1 = *(const int4*)&lst[e + 4];
        i0 = a0.x; i1 = a0.y; i2 = a0.z; i3 = a0.w;
        i4 = a1.x; i5 = a1.y; i6 = a1.z; i7 = a1.w;
      }
      uint4 w0 = *(const uint4*)&xb[(size_t)i0 * HDIM + 8 * q];
      uint4 w1 = *(const uint4*)&xb[(size_t)i1 * HDIM + 8 * q];
      uint4 w2 = *(const uint4*)&xb[(size_t)i2 * HDIM + 8 * q];
      uint4 w3 = *(const uint4*)&xb[(size_t)i3 * HDIM + 8 * q];
      uint4 w4 = *(const uint4*)&xb[(size_t)i4 * HDIM + 8 * q];
      uint4 w5 = *(const uint4*)&xb[(size_t)i5 * HDIM + 8 * q];
      uint4 w6 = *(const uint4*)&xb[(size_t)i6 * HDIM + 8 * q];
      uint4 w7 = *(const uint4*)&xb[(size_t)i7 * HDIM + 8 * q];
      acc8(a, b, w0);
      acc8(a, b, w1);
      acc8(a, b, w2);
      acc8(a, b, w3);
      acc8(a, b, w4);
      acc8(a, b, w5);
      acc8(a, b, w6);
      acc8(a, b, w7);
    }
    // 4-wide tail
    if (e + 4 <= nb) {
      int i0, i1, i2, i3;
      if (sizeof(IT) == 2) {
        ushort4 ia = *(const ushort4*)&lst[e];
        i0 = ia.x; i1 = ia.y; i2 = ia.z; i3 = ia.w;
      } else {
        int4 ia = *(const int4*)&lst[e];
        i0 = ia.x; i1 = ia.y; i2 = ia.z; i3 = ia.w;
      }
      uint4 w0 = *(const uint4*)&xb[(size_t)i0 * HDIM + 8 * q];
      uint4 w1 = *(const uint4*)&xb[(size_t)i1 * HDIM + 8 * q];
      uint4 w2 = *(const uint4*)&xb[(size_t)i2 * HDIM + 8 * q];
      uint4 w3 = *(const uint4*)&xb[(size_t)i3 * HDIM + 8 * q];
      acc8(a, b, w0);
      acc8(a, b, w1);
      acc8(a, b, w2);
      acc8(a, b, w3);
      e += 4;
    }
    for (; e < nb; ++e) {
      uint4 w0 = *(const uint4*)&xb[(size_t)lst[e] * HDIM + 8 * q];
      acc8(a, b, w0);
    }
    float inv = deg > 0 ? 1.f / (float)deg : 0.f;
    a.x *= inv; a.y *= inv; a.z *= inv; a.w *= inv;
    b.x *= inv; b.y *= inv; b.z *= inv; b.w *= inv;
    *(float4*)&agg[(size_t)node * HDIM + 8 * q] = a;
    *(float4*)&agg[(size_t)node * HDIM + 8 * q + 4] = b;
  }
}

// ---------------- overflow fixup (combined; normally a no-op) ----------------
__device__ __forceinline__ void fix_body(const int* __restrict__ cnt_p,
                                         const int* __restrict__ ovf,
                                         const unsigned short* __restrict__ xb,
                                         const int* __restrict__ cur,
                                         float* __restrict__ agg,
                                         int bid, int nblk) {
  int n = *cnt_p;
  if (n > OVF_MAX) n = OVF_MAX;
  int tid = bid * 256 + threadIdx.x;
  int q = tid & 15;
  int p = tid >> 4;
  int stride = (nblk * 256) >> 4;
  for (; p < n; p += stride) {
    int d = ovf[2 * p];
    int s = ovf[2 * p + 1];
    float inv = 1.f / (float)cur[d];
    ushort4 v = *(const ushort4*)&xb[(size_t)s * HDIM + 4 * q];
    atomicAdd(&agg[(size_t)d * HDIM + 4 * q + 0], bf2f(v.x) * inv);
    atomicAdd(&agg[(size_t)d * HDIM + 4 * q + 1], bf2f(v.y) * inv);
    atomicAdd(&agg[(size_t)d * HDIM + 4 * q + 2], bf2f(v.z) * inv);
    atomicAdd(&agg[(size_t)d * HDIM + 4 * q + 3], bf2f(v.w) * inv);
  }
}

__global__ __launch_bounds__(256) void k_fix2(const int* __restrict__ cntM,
                                              const int* __restrict__ ovfM,
                                              const unsigned short* __restrict__ xbM,
                                              const int* __restrict__ curM,
                                              float* __restrict__ aggM,
                                              const int* __restrict__ cntU,
                                              const int* __restrict__ ovfU,
                                              const unsigned short* __restrict__ xbU,
                                              const int* __restrict__ curU,
                                              float* __restrict__ aggU) {
  if (blockIdx.x < 16) fix_body(cntM, ovfM, xbM, curM, aggM, blockIdx.x, 16);
  else                 fix_body(cntU, ovfU, xbU, curU, aggU, blockIdx.x - 16, 16);
}

// ---------------- MFMA transform (r13 proven): out = [agg|X] @ [Wl;Wr] + b ----------------
template <int OUTBF>
__global__ __launch_bounds__(256) void k_xmfma(const float* A,
                                               const unsigned short* X,
                                               const float* __restrict__ Wl,
                                               const float* __restrict__ Wr,
                                               const float* __restrict__ bias,
                                               void* outv,
                                               int n_dst, int do_relu) {
  __shared__ unsigned short sWt[64][136];  // W^T bf16, padded
  __shared__ float sOut[4][16][68];        // per-wave C staging

  int t = threadIdx.x;
  for (int id = t; id < 64 * 128; id += 256) {
    int col = id & 63;
    int k = id >> 6;
    float wv = (k < 64) ? Wl[k * 64 + col] : Wr[(k - 64) * 64 + col];
    sWt[col][k] = f2bf(wv);
  }
  __syncthreads();

  int w = t >> 6;
  int l = t & 63;
  int lm = l & 15;
  int lg = l >> 4;
  int wid = blockIdx.x * 4 + w;
  int nw = gridDim.x * 4;
  int ntiles = (n_dst + 15) >> 4;

  for (int tile = wid; tile < ntiles; tile += nw) {
    int nbase = tile << 4;
    int row = nbase + lm;
    int rowc = row < n_dst ? row : (n_dst - 1);

    bf16x8 afr[4];
    const float* ar = A + (size_t)rowc * HDIM;
#pragma unroll
    for (int s = 0; s < 2; ++s) {
      float4 f0 = *(const float4*)(ar + 32 * s + 8 * lg);
      float4 f1 = *(const float4*)(ar + 32 * s + 8 * lg + 4);
      bf16x8 v;
      v[0] = (short)f2bf(f0.x); v[1] = (short)f2bf(f0.y);
      v[2] = (short)f2bf(f0.z); v[3] = (short)f2bf(f0.w);
      v[4] = (short)f2bf(f1.x); v[5] = (short)f2bf(f1.y);
      v[6] = (short)f2bf(f1.z); v[7] = (short)f2bf(f1.w);
      afr[s] = v;
    }
    const unsigned short* xr = X + (size_t)rowc * HDIM;
#pragma unroll
    for (int s = 0; s < 2; ++s) {
      afr[2 + s] = *(const bf16x8*)(xr + 32 * s + 8 * lg);
    }

    f32x4 zz = {0.f, 0.f, 0.f, 0.f};
    f32x4 acc[4];
#pragma unroll
    for (int n = 0; n < 4; ++n) acc[n] = zz;
#pragma unroll
    for (int s = 0; s < 4; ++s) {
#pragma unroll
      for (int n = 0; n < 4; ++n) {
        bf16x8 bfr = *(const bf16x8*)(&sWt[16 * n + lm][32 * s + 8 * lg]);
        acc[n] = __builtin_amdgcn_mfma_f32_16x16x32_bf16(afr[s], bfr, acc[n], 0, 0, 0);
      }
    }

#pragma unroll
    for (int n = 0; n < 4; ++n) {
      float bj = bias[16 * n + lm];
#pragma unroll
      for (int r = 0; r < 4; ++r) {
        float v = acc[n][r] + bj;
        if (do_relu) v = fmaxf(v, 0.f);
        sOut[w][lg * 4 + r][16 * n + lm] = v;
      }
    }

    int node = nbase + (l >> 2);
    if (node < n_dst) {
      int c0 = (l & 3) * 16;
      float4 o0 = *(const float4*)&sOut[w][l >> 2][c0];
      float4 o1 = *(const float4*)&sOut[w][l >> 2][c0 + 4];
      float4 o2 = *(const float4*)&sOut[w][l >> 2][c0 + 8];
      float4 o3 = *(const float4*)&sOut[w][l >> 2][c0 + 12];
      if (OUTBF) {
        unsigned short* ob = (unsigned short*)outv;
        uint4 p0, p1;
        p0.x = (unsigned int)f2bf(o0.x) | ((unsigned int)f2bf(o0.y) << 16);
        p0.y = (unsigned int)f2bf(o0.z) | ((unsigned int)f2bf(o0.w) << 16);
        p0.z = (unsigned int)f2bf(o1.x) | ((unsigned int)f2bf(o1.y) << 16);
        p0.w = (unsigned int)f2bf(o1.z) | ((unsigned int)f2bf(o1.w) << 16);
        p1.x = (unsigned int)f2bf(o2.x) | ((unsigned int)f2bf(o2.y) << 16);
        p1.y = (unsigned int)f2bf(o2.z) | ((unsigned int)f2bf(o2.w) << 16);
        p1.z = (unsigned int)f2bf(o3.x) | ((unsigned int)f2bf(o3.y) << 16);
        p1.w = (unsigned int)f2bf(o3.z) | ((unsigned int)f2bf(o3.w) << 16);
        *(uint4*)&ob[(size_t)node * HDIM + c0] = p0;
        *(uint4*)&ob[(size_t)node * HDIM + c0 + 8] = p1;
      } else {
        float* of = (float*)outv;
        *(float4*)&of[(size_t)node * HDIM + c0] = o0;
        *(float4*)&of[(size_t)node * HDIM + c0 + 4] = o1;
        *(float4*)&of[(size_t)node * HDIM + c0 + 8] = o2;
        *(float4*)&of[(size_t)node * HDIM + c0 + 12] = o3;
      }
    }
  }
}

// ---------------- launch ----------------

static inline int imin(int a, int b) { return a < b ? a : b; }

extern "C" void kernel_launch(void* const* d_in, const int* in_sizes, int n_in,
                              void* d_out, int out_size, void* d_ws, size_t ws_size,
                              hipStream_t stream) {
  const int NU = in_sizes[0];
  const int NM = in_sizes[1];
  const int E  = in_sizes[2];

  const int* src_um = (const int*)d_in[2];
  const int* dst_um = (const int*)d_in[3];
  const float* user_table  = (const float*)d_in[6];
  const float* movie_table = (const float*)d_in[7];
  const float* Wl1_um = (const float*)d_in[8];
  const float* Wr1_um = (const float*)d_in[9];
  const float* Wl1_mu = (const float*)d_in[10];
  const float* Wr1_mu = (const float*)d_in[11];
  const float* Wl2_um = (const float*)d_in[12];
  const float* Wr2_um = (const float*)d_in[13];
  const float* Wl2_mu = (const float*)d_in[14];
  const float* Wr2_mu = (const float*)d_in[15];
  const float* b1_um = (const float*)d_in[16];
  const float* b1_mu = (const float*)d_in[17];
  const float* b2_um = (const float*)d_in[18];
  const float* b2_mu = (const float*)d_in[19];

  float* out_u2 = (float*)d_out;                       // [NU,64]
  float* out_m2 = (float*)d_out + (size_t)NU * HDIM;   // [NM,64]
  float* aggu = out_u2;   // agg scratch in d_out; layer2 xform in-place per-row
  float* aggm = out_m2;

  // workspace carve (256B aligned); total ~61 MB
  char* ws = (char*)d_ws;
  size_t off = 0;
  auto carve = [&](size_t bytes) -> char* {
    char* p = ws + off;
    off = (off + bytes + 255) & ~(size_t)255;
    return p;
  };
  int* meta = (int*)carve((size_t)(NM + NU + 2) * 4);
  int* curm = meta;
  int* curu = meta + NM;
  int* ovfm_cnt = meta + NM + NU;
  int* ovfu_cnt = meta + NM + NU + 1;
  int nmeta = NM + NU + 2;
  int* ovfm = (int*)carve((size_t)OVF_MAX * 2 * 4);
  int* ovfu = (int*)carve((size_t)OVF_MAX * 2 * 4);
  int* bktm = (int*)carve((size_t)NM * CAP_M * 4);                        // user ids (int)
  unsigned short* bktu = (unsigned short*)carve((size_t)NU * CAP_U * 2);  // movie ids (ushort)
  unsigned short* mb = (unsigned short*)carve((size_t)NM * HDIM * 2);     // bf16 movie tbl -> m1
  unsigned short* ub = (unsigned short*)carve((size_t)NU * HDIM * 2);     // bf16 user tbl -> u1
  (void)ws_size;

  const int TB = 256;

  // 0) init: zero counters + bf16 table copies (one streaming dispatch)
  int n8u = NU * HDIM / 8, n8m = NM * HDIM / 8;
  k_init<<<3072, TB, 0, stream>>>(meta, nmeta, user_table, ub, n8u,
                                  movie_table, mb, n8m);

  // 1) fused bucket fill
  k_fillb2_x<<<2048, TB, 0, stream>>>(src_um, dst_um,
                                      curm, bktm, ovfm_cnt, ovfm,
                                      curu, bktu, ovfu_cnt, ovfu,
                                      E, NM, NU);

  int gAm = imin((NM + 31) / 32, 8192);
  int gAu = imin((NU + 31) / 32, 8192);
  int gXm = (NM + 63) / 64;   // 64 nodes/block (4 waves x 16)
  int gXu = (NU + 63) / 64;

  // 2) layer 1 (relu): serial aggs (r9 lesson), fix, MFMA xforms (in-place bf16)
  k_agg8<int><<<gAm, TB, 0, stream>>>(ub, curm, bktm, CAP_M, aggm, NM);
  k_agg8<unsigned short><<<gAu, TB, 0, stream>>>(mb, curu, bktu, CAP_U, aggu, NU);
  k_fix2<<<32, TB, 0, stream>>>(ovfm_cnt, ovfm, ub, curm, aggm,
                                ovfu_cnt, ovfu, mb, curu, aggu);
  k_xmfma<1><<<gXm, TB, 0, stream>>>(aggm, mb, Wl1_um, Wr1_um, b1_um,
                                     mb, NM, 1);   // mb becomes m1 (bf16)
  k_xmfma<1><<<gXu, TB, 0, stream>>>(aggu, ub, Wl1_mu, Wr1_mu, b1_mu,
                                     ub, NU, 1);   // ub becomes u1 (bf16)

  // 3) layer 2 (no relu): aggs into d_out, MFMA xforms in-place -> fp32 out
  k_agg8<int><<<gAm, TB, 0, stream>>>(ub, curm, bktm, CAP_M, aggm, NM);
  k_agg8<unsigned short><<<gAu, TB, 0, stream>>>(mb, curu, bktu, CAP_U, aggu, NU);
  k_fix2<<<32, TB, 0, stream>>>(ovfm_cnt, ovfm, ub, curm, aggm,
                                ovfu_cnt, ovfu, mb, curu, aggu);
  k_xmfma<0><<<gXm, TB, 0, stream>>>(aggm, mb, Wl2_um, Wr2_um, b2_um,
                                     out_m2, NM, 0);
  k_xmfma<0><<<gXu, TB, 0, stream>>>(aggu, ub, Wl2_mu, Wr2_mu, b2_mu,
                                     out_u2, NU, 0);
}